// Round 7
// baseline (2735.596 us; speedup 1.0000x reference)
//
#include <hip/hip_runtime.h>
#include <hip/hip_bf16.h>

#define NN 100000
#define NE 800000
#define NG 2048
#define DIN 74
#define KPAD 96
#define DH 256
#define DM1 1024
#define DM2 512

typedef __attribute__((ext_vector_type(8))) short short8;
typedef __attribute__((ext_vector_type(4))) float f32x4;

__device__ inline ushort f2bf(float f) {
  unsigned u = __float_as_uint(f);
  return (ushort)((u + 0x7fffu + ((u >> 16) & 1u)) >> 16);
}
__device__ inline float bf2f(ushort h) { return __uint_as_float(((unsigned)h) << 16); }
__device__ inline uint packhl(float v) {
  ushort hv = f2bf(v);
  ushort lv = f2bf(v - bf2f(hv));
  return ((uint)hv << 16) | (uint)lv;
}
__device__ inline float unpackhl(uint u) {
  return __uint_as_float(u & 0xffff0000u) + __uint_as_float(u << 16);
}

// async 16B/lane global->LDS: lds dest is wave-uniform base + lane*16
__device__ inline void gll16(const ushort* g, ushort* l) {
  __builtin_amdgcn_global_load_lds((const __attribute__((address_space(1))) void*)g,
                                   (__attribute__((address_space(3))) void*)l, 16, 0, 0);
}

// ---------------- degrees & norms ----------------
__global__ void k_deg(const int* __restrict__ src, const int* __restrict__ dst,
                      int* __restrict__ outd, int* __restrict__ ind) {
  int e = blockIdx.x * blockDim.x + threadIdx.x;
  if (e < NE) {
    atomicAdd(&outd[src[e]], 1);
    atomicAdd(&ind[dst[e]], 1);
  }
}

__global__ void k_norm(const int* __restrict__ outd, const int* __restrict__ ind,
                       float* __restrict__ onorm, float* __restrict__ inorm) {
  int i = blockIdx.x * blockDim.x + threadIdx.x;
  if (i < NN) {
    onorm[i] = rsqrtf(fmaxf((float)outd[i], 1.f));
    inorm[i] = rsqrtf(fmaxf((float)ind[i], 1.f));
  }
}

// ---------------- CSR build (scan + counting sort) ----------------
__global__ void k_scan_block(const int* __restrict__ deg, int* __restrict__ incl,
                             int* __restrict__ bsum, int n) {
  __shared__ int s[1024];
  int t = threadIdx.x;
  int i = blockIdx.x * 1024 + t;
  int v = (i < n) ? deg[i] : 0;
  s[t] = v;
  __syncthreads();
  for (int off = 1; off < 1024; off <<= 1) {
    int x = (t >= off) ? s[t - off] : 0;
    __syncthreads();
    s[t] += x;
    __syncthreads();
  }
  if (i < n) incl[i] = s[t];
  if (t == 1023) bsum[blockIdx.x] = s[1023];
}

// single-wave exclusive scan of block sums (nb <= 128)
__global__ void k_scan_sums(int* bsum, int nb) {
  int lane = threadIdx.x & 63;
  int i0 = 2 * lane, i1 = 2 * lane + 1;
  int v0 = (i0 < nb) ? bsum[i0] : 0;
  int v1 = (i1 < nb) ? bsum[i1] : 0;
  int s = v0 + v1;
  for (int off = 1; off < 64; off <<= 1) {
    int t = __shfl_up(s, off);
    if (lane >= off) s += t;
  }
  int excl = s - (v0 + v1);
  if (i0 < nb) bsum[i0] = excl;
  if (i1 < nb) bsum[i1] = excl + v0;
}

__global__ void k_scan_add(const int* __restrict__ incl, const int* __restrict__ bsum,
                           const int* __restrict__ deg,
                           int* __restrict__ offs, int* __restrict__ cursor, int n) {
  int i = blockIdx.x * blockDim.x + threadIdx.x;
  if (i < n) {
    int v = incl[i] + bsum[i >> 10];
    offs[i + 1] = v;
    cursor[i] = v - deg[i];
    if (i == 0) offs[0] = 0;
  }
}

__global__ void k_scatter(const int* __restrict__ src, const int* __restrict__ dst,
                          int* __restrict__ cursor, int* __restrict__ ssrc) {
  int e = blockIdx.x * blockDim.x + threadIdx.x;
  if (e < NE) {
    int pos = atomicAdd(&cursor[dst[e]], 1);
    ssrc[pos] = src[e];
  }
}

// ---------------- weight convert: fp32 [k][n] -> bf16 hi/lo planes [n][k] ----------------
__global__ void k_convw(const float* __restrict__ W_in, const float* __restrict__ W_gcr,
                        const float* __restrict__ W1, const float* __restrict__ W2,
                        ushort* __restrict__ Wt0h, ushort* __restrict__ Wt0l,
                        ushort* __restrict__ Wtgh, ushort* __restrict__ Wtgl,
                        ushort* __restrict__ Wt1h, ushort* __restrict__ Wt1l,
                        ushort* __restrict__ Wt2h, ushort* __restrict__ Wt2l) {
  int idx = blockIdx.x * blockDim.x + threadIdx.x;
  const int n0 = 256 * KPAD;
  const int n1 = n0 + 10 * 65536;
  const int n2 = n1 + DM1 * DH;
  const int n3 = n2 + DM2 * DM1;
  float v;
  ushort *dh, *dl;
  int o;
  if (idx < n0) {
    int n = idx / KPAD, k = idx - n * KPAD;
    v = (k < DIN) ? W_in[k * DH + n] : 0.f;
    dh = Wt0h; dl = Wt0l; o = idx;
  } else if (idx < n1) {
    int j = idx - n0;
    int l = j >> 16, r = j & 65535;
    int n = r >> 8, k = r & 255;
    v = W_gcr[l * 65536 + k * 256 + n];
    dh = Wtgh; dl = Wtgl; o = l * 65536 + n * 256 + k;
  } else if (idx < n2) {
    int j = idx - n1;
    int n = j >> 8, k = j & 255;
    v = W1[k * DM1 + n];
    dh = Wt1h; dl = Wt1l; o = n * 256 + k;
  } else if (idx < n3) {
    int j = idx - n2;
    int n = j >> 10, k = j & 1023;
    v = W2[k * DM2 + n];
    dh = Wt2h; dl = Wt2l; o = n * 1024 + k;
  } else {
    return;
  }
  ushort hv = f2bf(v);
  dh[o] = hv;
  dl[o] = f2bf(v - bf2f(hv));
}

// ---------------- SpMM (gather by dst row, wave per row) ----------------
__global__ void k_spmm74(const float* __restrict__ h, const int* __restrict__ offs,
                         const int* __restrict__ ssrc, const float* __restrict__ onorm,
                         const float* __restrict__ inorm,
                         ushort* __restrict__ Ahi, ushort* __restrict__ Alo) {
  int row = blockIdx.x * 4 + (threadIdx.x >> 6);
  if (row >= NN) return;
  int lane = threadIdx.x & 63;
  int beg = offs[row], end = offs[row + 1];
  float a0 = 0.f, a1 = 0.f;
  for (int e = beg; e < end; ++e) {
    int s = ssrc[e];
    float w = onorm[s];
    const float* hr = h + (size_t)s * DIN;
    a0 += w * hr[lane];
    if (lane < DIN - 64) a1 += w * hr[64 + lane];
  }
  float win = inorm[row];
  ushort* ph = Ahi + (size_t)row * KPAD;
  ushort* pl = Alo + (size_t)row * KPAD;
  float v0 = a0 * win;
  ushort h0 = f2bf(v0);
  ph[lane] = h0;
  pl[lane] = f2bf(v0 - bf2f(h0));
  if (lane < DIN - 64) {
    float v1 = a1 * win;
    ushort h1 = f2bf(v1);
    ph[64 + lane] = h1;
    pl[64 + lane] = f2bf(v1 - bf2f(h1));
  } else if (lane < KPAD - 64) {
    ph[64 + lane] = 0;
    pl[64 + lane] = 0;
  }
}

// half-column gather pass: k in [kbase, kbase+128). Working set 50 MB -> L3-resident.
// depth-4 edge pipeline, uint2 (8B) per lane per edge.
__global__ void k_spmm256(const uint* __restrict__ xp, const int* __restrict__ offs,
                          const int* __restrict__ ssrc, const float* __restrict__ onorm,
                          const float* __restrict__ inorm,
                          ushort* __restrict__ Ahi, ushort* __restrict__ Alo,
                          int kbase) {
  int row = blockIdx.x * 4 + (threadIdx.x >> 6);
  if (row >= NN) return;
  int lane = threadIdx.x & 63;
  int beg = offs[row], n = offs[row + 1] - beg;
  float a0 = 0.f, a1 = 0.f;
  float w0 = 0.f, w1 = 0.f, w2 = 0.f, w3 = 0.f;
  uint2 z = {0, 0};
  uint2 u0 = z, u1 = z, u2 = z, u3 = z;
#define LOADJ(wj, uj, idx) { int s_ = ssrc[idx]; wj = onorm[s_]; \
    uj = *(const uint2*)(xp + (size_t)s_ * DH + kbase + lane * 2); }
  if (n > 0) LOADJ(w0, u0, beg)
  if (n > 1) LOADJ(w1, u1, beg + 1)
  if (n > 2) LOADJ(w2, u2, beg + 2)
  if (n > 3) LOADJ(w3, u3, beg + 3)
  int e = 0;
#define STEP(wj, uj) { float fw = wj; uint2 fu = uj; \
    if (e + 4 < n) LOADJ(wj, uj, beg + e + 4) \
    a0 += fw * unpackhl(fu.x); a1 += fw * unpackhl(fu.y); ++e; }
  while (e < n) {
    STEP(w0, u0) if (e >= n) break;
    STEP(w1, u1) if (e >= n) break;
    STEP(w2, u2) if (e >= n) break;
    STEP(w3, u3)
  }
#undef STEP
#undef LOADJ
  float win = inorm[row];
  float o0 = a0 * win, o1 = a1 * win;
  ushort2 hv, lv;
  hv.x = f2bf(o0); lv.x = f2bf(o0 - bf2f(hv.x));
  hv.y = f2bf(o1); lv.y = f2bf(o1 - bf2f(hv.y));
  *(ushort2*)(Ahi + (size_t)row * DH + kbase + lane * 2) = hv;
  *(ushort2*)(Alo + (size_t)row * DH + kbase + lane * 2) = lv;
}

// ---------------- async-staged bf16x3 MFMA GEMM, 128x256 tile, 512 threads ----------------
// A: hi/lo planes [M][K]; B: hi/lo planes [N][K] (k-contiguous). N tile 256 -> A read once.
// Staging via global_load_lds (16B/lane, wave-uniform LDS base). LDS layout unpadded
// 32-ushort rows with XOR chunk swizzle c_lds = c ^ ((row>>1)&3) -> 2-way (free) frag reads.
// ACT: 0=none 1=relu 2=leaky(0.01). OUT: 0=fp32 C0, 1=packed hi|lo uint C0, 2=planes C0/C1
template <int ACT, int OUT>
__global__ __launch_bounds__(512, 4) void k_mfma(
    const ushort* __restrict__ Ah, const ushort* __restrict__ Al,
    const ushort* __restrict__ Bh, const ushort* __restrict__ Bl,
    const float* __restrict__ bias, void* __restrict__ C0, void* __restrict__ C1,
    int M, int K, int Nc) {
  __shared__ __align__(16) ushort Ash[128 * 32], Asl[128 * 32];
  __shared__ __align__(16) ushort Bsh[256 * 32], Bsl[256 * 32];
  const int tid = threadIdx.x, lane = tid & 63, wv = tid >> 6;
  const int wm = (wv >> 2) * 64, wn = (wv & 3) * 64;
  const int quad = lane >> 4, l15 = lane & 15;
  const int r0 = blockIdx.x * 128, c0 = blockIdx.y * 256;

  // staging lane map: 16-row chunk per wave-issue; lane -> (row=lane>>2, chunk=lane&3)
  const int srow = lane >> 2, clds = lane & 3;
  const int arow = 16 * wv + srow;
  const int acg = clds ^ ((arow >> 1) & 3);            // global chunk landing at clds
  int agr = r0 + arow; if (agr > M - 1) agr = M - 1;   // clamp; epilogue masks stores
  const size_t aoff = (size_t)agr * K + acg * 8;
  const int brow0 = 16 * wv + srow, brow1 = brow0 + 128;
  const int bcg0 = clds ^ ((brow0 >> 1) & 3);
  const int bcg1 = clds ^ ((brow1 >> 1) & 3);
  const size_t boff0 = (size_t)(c0 + brow0) * K + bcg0 * 8;
  const size_t boff1 = (size_t)(c0 + brow1) * K + bcg1 * 8;
  ushort* lAh = &Ash[(16 * wv) * 32];
  ushort* lAl = &Asl[(16 * wv) * 32];
  ushort* lB0h = &Bsh[(16 * wv) * 32];
  ushort* lB0l = &Bsl[(16 * wv) * 32];
  ushort* lB1h = &Bsh[(16 * wv + 128) * 32];
  ushort* lB1l = &Bsl[(16 * wv + 128) * 32];

  f32x4 acc[4][4] = {};
  const int nk = K >> 5;
  for (int s = 0; s < nk; ++s) {
    const int k0 = s << 5;
    __syncthreads();  // previous tile fully consumed
    gll16(Ah + aoff + k0, lAh);
    gll16(Al + aoff + k0, lAl);
    gll16(Bh + boff0 + k0, lB0h);
    gll16(Bl + boff0 + k0, lB0l);
    gll16(Bh + boff1 + k0, lB1h);
    gll16(Bl + boff1 + k0, lB1l);
    __syncthreads();  // vmcnt drained by compiler before barrier -> tile visible
    short8 ah[4], al[4];
#pragma unroll
    for (int t = 0; t < 4; ++t) {
      int r = wm + t * 16 + l15;
      int sa = (quad ^ ((r >> 1) & 3)) << 3;
      ah[t] = *(const short8*)&Ash[r * 32 + sa];
      al[t] = *(const short8*)&Asl[r * 32 + sa];
    }
#pragma unroll
    for (int nt = 0; nt < 4; ++nt) {
      int rb = wn + nt * 16 + l15;
      int sb = (quad ^ ((rb >> 1) & 3)) << 3;
      short8 bh = *(const short8*)&Bsh[rb * 32 + sb];
      short8 bl = *(const short8*)&Bsl[rb * 32 + sb];
#pragma unroll
      for (int mt = 0; mt < 4; ++mt) {
        acc[mt][nt] = __builtin_amdgcn_mfma_f32_16x16x32_bf16(ah[mt], bh, acc[mt][nt], 0, 0, 0);
        acc[mt][nt] = __builtin_amdgcn_mfma_f32_16x16x32_bf16(ah[mt], bl, acc[mt][nt], 0, 0, 0);
        acc[mt][nt] = __builtin_amdgcn_mfma_f32_16x16x32_bf16(al[mt], bh, acc[mt][nt], 0, 0, 0);
      }
    }
  }

  float bv[4];
#pragma unroll
  for (int nt = 0; nt < 4; ++nt) bv[nt] = bias[c0 + wn + nt * 16 + l15];
#pragma unroll
  for (int mt = 0; mt < 4; ++mt) {
#pragma unroll
    for (int r = 0; r < 4; ++r) {
      int gr = r0 + wm + mt * 16 + quad * 4 + r;
      if (gr >= M) continue;
#pragma unroll
      for (int nt = 0; nt < 4; ++nt) {
        int gc = c0 + wn + nt * 16 + l15;
        float v = acc[mt][nt][r] + bv[nt];
        if (ACT == 1) v = fmaxf(v, 0.f);
        if (ACT == 2) v = (v > 0.f) ? v : 0.01f * v;
        size_t idx = (size_t)gr * Nc + gc;
        if (OUT == 0) {
          ((float*)C0)[idx] = v;
        } else if (OUT == 1) {
          ((uint*)C0)[idx] = packhl(v);
        } else {
          ushort hv = f2bf(v);
          ((ushort*)C0)[idx] = hv;
          ((ushort*)C1)[idx] = f2bf(v - bf2f(hv));
        }
      }
    }
  }
}

// ---------------- pooling + tail ----------------
__global__ void k_gbounds(const int* __restrict__ gid, int* __restrict__ gstart) {
  int g = blockIdx.x * blockDim.x + threadIdx.x;
  if (g > NG) return;
  int lo = 0, hi = NN;
  while (lo < hi) {
    int mid = (lo + hi) >> 1;
    if (gid[mid] < g) lo = mid + 1; else hi = mid;
  }
  gstart[g] = lo;
}

__global__ void k_pool(const uint* __restrict__ xp, const int* __restrict__ gstart,
                       ushort* __restrict__ ph, ushort* __restrict__ pl) {
  int g = blockIdx.x * 4 + (threadIdx.x >> 6);
  if (g >= NG) return;
  int lane = threadIdx.x & 63;
  int beg = gstart[g], end = gstart[g + 1];
  float a0 = 0.f, a1 = 0.f, a2 = 0.f, a3 = 0.f;
  for (int r = beg; r < end; ++r) {
    uint4 u = *(const uint4*)(xp + (size_t)r * DH + lane * 4);
    a0 += unpackhl(u.x);
    a1 += unpackhl(u.y);
    a2 += unpackhl(u.z);
    a3 += unpackhl(u.w);
  }
  float inv = 1.f / fmaxf((float)(end - beg), 1.f);
  float o[4] = {a0 * inv, a1 * inv, a2 * inv, a3 * inv};
  ushort4 hv, lv;
  hv.x = f2bf(o[0]); lv.x = f2bf(o[0] - bf2f(hv.x));
  hv.y = f2bf(o[1]); lv.y = f2bf(o[1] - bf2f(hv.y));
  hv.z = f2bf(o[2]); lv.z = f2bf(o[2] - bf2f(hv.z));
  hv.w = f2bf(o[3]); lv.w = f2bf(o[3] - bf2f(hv.w));
  *(ushort4*)(ph + (size_t)g * DH + lane * 4) = hv;
  *(ushort4*)(pl + (size_t)g * DH + lane * 4) = lv;
}

__global__ void k_out(const float* __restrict__ z2, const float* __restrict__ W3,
                      const float* __restrict__ b3, float* __restrict__ out) {
  int g = blockIdx.x * 4 + (threadIdx.x >> 6);
  if (g >= NG) return;
  int lane = threadIdx.x & 63;
  float s = 0.f;
  const float* zr = z2 + (size_t)g * DM2;
  for (int k = lane; k < DM2; k += 64) s += zr[k] * W3[k];
  for (int off = 32; off > 0; off >>= 1) s += __shfl_down(s, off);
  if (lane == 0) out[g] = s + b3[0];
}

// ---------------- launcher ----------------
extern "C" void kernel_launch(void* const* d_in, const int* in_sizes, int n_in,
                              void* d_out, int out_size, void* d_ws, size_t ws_size,
                              hipStream_t stream) {
  (void)in_sizes; (void)n_in; (void)out_size; (void)ws_size;
  const float* h     = (const float*)d_in[0];
  const int*   src   = (const int*)d_in[1];
  const int*   dst   = (const int*)d_in[2];
  const int*   gid   = (const int*)d_in[3];
  const float* W_in  = (const float*)d_in[4];
  const float* b_in  = (const float*)d_in[5];
  const float* W_gcr = (const float*)d_in[6];
  const float* b_gcr = (const float*)d_in[7];
  const float* W1    = (const float*)d_in[8];
  const float* b1    = (const float*)d_in[9];
  const float* W2    = (const float*)d_in[10];
  const float* b2    = (const float*)d_in[11];
  const float* W3    = (const float*)d_in[12];
  const float* b3    = (const float*)d_in[13];
  float* out = (float*)d_out;

  char* p = (char*)d_ws;
  auto alloc = [&](size_t bytes) {
    char* q = p;
    p += (bytes + 255) & ~(size_t)255;
    return q;
  };
  int*    outdeg = (int*)alloc((size_t)NN * 4);
  int*    indeg  = (int*)alloc((size_t)NN * 4);
  float*  onorm  = (float*)alloc((size_t)NN * 4);
  float*  inorm  = (float*)alloc((size_t)NN * 4);
  int*    incl   = (int*)alloc((size_t)NN * 4);
  int*    bsum   = (int*)alloc(128 * 4);
  int*    offs   = (int*)alloc((size_t)(NN + 1) * 4);
  int*    cursor = (int*)alloc((size_t)NN * 4);
  int*    ssrc   = (int*)alloc((size_t)NE * 4);
  int*    gstart = (int*)alloc((size_t)(NG + 1) * 4);
  uint*   xp     = (uint*)alloc((size_t)NN * DH * 4);
  ushort* Ahi    = (ushort*)alloc((size_t)NN * DH * 2);
  ushort* Alo    = (ushort*)alloc((size_t)NN * DH * 2);
  ushort* Wt0h   = (ushort*)alloc((size_t)256 * KPAD * 2);
  ushort* Wt0l   = (ushort*)alloc((size_t)256 * KPAD * 2);
  ushort* Wtgh   = (ushort*)alloc((size_t)10 * 65536 * 2);
  ushort* Wtgl   = (ushort*)alloc((size_t)10 * 65536 * 2);
  ushort* Wt1h   = (ushort*)alloc((size_t)DM1 * DH * 2);
  ushort* Wt1l   = (ushort*)alloc((size_t)DM1 * DH * 2);
  ushort* Wt2h   = (ushort*)alloc((size_t)DM2 * DM1 * 2);
  ushort* Wt2l   = (ushort*)alloc((size_t)DM2 * DM1 * 2);
  ushort* plh    = (ushort*)alloc((size_t)NG * DH * 2);
  ushort* pll    = (ushort*)alloc((size_t)NG * DH * 2);
  ushort* z1h    = (ushort*)alloc((size_t)NG * DM1 * 2);
  ushort* z1l    = (ushort*)alloc((size_t)NG * DM1 * 2);
  float*  z2     = (float*)alloc((size_t)NG * DM2 * 4);

  hipMemsetAsync(outdeg, 0, (size_t)NN * 4, stream);
  hipMemsetAsync(indeg, 0, (size_t)NN * 4, stream);
  k_deg<<<(NE + 255) / 256, 256, 0, stream>>>(src, dst, outdeg, indeg);
  k_norm<<<(NN + 255) / 256, 256, 0, stream>>>(outdeg, indeg, onorm, inorm);
  int nb = (NN + 1023) / 1024;
  k_scan_block<<<nb, 1024, 0, stream>>>(indeg, incl, bsum, NN);
  k_scan_sums<<<1, 64, 0, stream>>>(bsum, nb);
  k_scan_add<<<(NN + 255) / 256, 256, 0, stream>>>(incl, bsum, indeg, offs, cursor, NN);
  k_scatter<<<(NE + 255) / 256, 256, 0, stream>>>(src, dst, cursor, ssrc);

  const int nconv = 256 * KPAD + 10 * 65536 + DM1 * DH + DM2 * DM1;
  k_convw<<<(nconv + 255) / 256, 256, 0, stream>>>(W_in, W_gcr, W1, W2,
                                                   Wt0h, Wt0l, Wtgh, Wtgl,
                                                   Wt1h, Wt1l, Wt2h, Wt2l);

  dim3 gmm((NN + 127) / 128, 1);  // N=256 covered by one column tile

  // input conv: aggregate 74 (pad 96), GEMM 96->256, no activation, packed output
  k_spmm74<<<(NN + 3) / 4, 256, 0, stream>>>(h, offs, ssrc, onorm, inorm, Ahi, Alo);
  k_mfma<0, 1><<<gmm, 512, 0, stream>>>(Ahi, Alo, Wt0h, Wt0l, b_in, xp, nullptr,
                                        NN, KPAD, DH);

  // 5 GCR blocks x 2 convs; relu fused into every conv GEMM epilogue.
  // spmm split into two half-column passes so each pass's gather footprint
  // (50 MB) stays L3-resident.
  for (int li = 0; li < 10; ++li) {
    k_spmm256<<<(NN + 3) / 4, 256, 0, stream>>>(xp, offs, ssrc, onorm, inorm,
                                                Ahi, Alo, 0);
    k_spmm256<<<(NN + 3) / 4, 256, 0, stream>>>(xp, offs, ssrc, onorm, inorm,
                                                Ahi, Alo, 128);
    k_mfma<1, 1><<<gmm, 512, 0, stream>>>(Ahi, Alo, Wtgh + (size_t)li * 65536,
                                          Wtgl + (size_t)li * 65536, b_gcr + li * 256,
                                          xp, nullptr, NN, DH, DH);
  }

  k_gbounds<<<(NG + 1 + 255) / 256, 256, 0, stream>>>(gid, gstart);
  k_pool<<<(NG + 3) / 4, 256, 0, stream>>>(xp, gstart, plh, pll);

  dim3 gt1(NG / 128, DM1 / 256);
  k_mfma<2, 2><<<gt1, 512, 0, stream>>>(plh, pll, Wt1h, Wt1l, b1, z1h, z1l,
                                        NG, DH, DM1);
  dim3 gt2(NG / 128, DM2 / 256);
  k_mfma<2, 0><<<gt2, 512, 0, stream>>>(z1h, z1l, Wt2h, Wt2l, b2, z2, nullptr,
                                        NG, DM1, DM2);
  k_out<<<(NG + 3) / 4, 256, 0, stream>>>(z2, W3, b3, out);
}

// Round 8
// 1849.475 us; speedup vs baseline: 1.4791x; 1.4791x over previous
//
#include <hip/hip_runtime.h>
#include <hip/hip_bf16.h>

#define NN 100000
#define NE 800000
#define NG 2048
#define DIN 74
#define KPAD 96
#define DH 256
#define DM1 1024
#define DM2 512

typedef __attribute__((ext_vector_type(8))) short short8;
typedef __attribute__((ext_vector_type(4))) float f32x4;

__device__ inline ushort f2bf(float f) {
  unsigned u = __float_as_uint(f);
  return (ushort)((u + 0x7fffu + ((u >> 16) & 1u)) >> 16);
}
__device__ inline float bf2f(ushort h) { return __uint_as_float(((unsigned)h) << 16); }

// async 16B/lane global->LDS: lds dest is wave-uniform base + lane*16
__device__ inline void gll16(const ushort* g, ushort* l) {
  __builtin_amdgcn_global_load_lds((const __attribute__((address_space(1))) void*)g,
                                   (__attribute__((address_space(3))) void*)l, 16, 0, 0);
}

// ---------------- degrees & norms ----------------
__global__ void k_deg(const int* __restrict__ src, const int* __restrict__ dst,
                      int* __restrict__ outd, int* __restrict__ ind) {
  int e = blockIdx.x * blockDim.x + threadIdx.x;
  if (e < NE) {
    atomicAdd(&outd[src[e]], 1);
    atomicAdd(&ind[dst[e]], 1);
  }
}

__global__ void k_norm(const int* __restrict__ outd, const int* __restrict__ ind,
                       float* __restrict__ onorm, float* __restrict__ inorm) {
  int i = blockIdx.x * blockDim.x + threadIdx.x;
  if (i < NN) {
    onorm[i] = rsqrtf(fmaxf((float)outd[i], 1.f));
    inorm[i] = rsqrtf(fmaxf((float)ind[i], 1.f));
  }
}

// ---------------- CSR build (scan + counting sort) ----------------
__global__ void k_scan_block(const int* __restrict__ deg, int* __restrict__ incl,
                             int* __restrict__ bsum, int n) {
  __shared__ int s[1024];
  int t = threadIdx.x;
  int i = blockIdx.x * 1024 + t;
  int v = (i < n) ? deg[i] : 0;
  s[t] = v;
  __syncthreads();
  for (int off = 1; off < 1024; off <<= 1) {
    int x = (t >= off) ? s[t - off] : 0;
    __syncthreads();
    s[t] += x;
    __syncthreads();
  }
  if (i < n) incl[i] = s[t];
  if (t == 1023) bsum[blockIdx.x] = s[1023];
}

// single-wave exclusive scan of block sums (nb <= 128)
__global__ void k_scan_sums(int* bsum, int nb) {
  int lane = threadIdx.x & 63;
  int i0 = 2 * lane, i1 = 2 * lane + 1;
  int v0 = (i0 < nb) ? bsum[i0] : 0;
  int v1 = (i1 < nb) ? bsum[i1] : 0;
  int s = v0 + v1;
  for (int off = 1; off < 64; off <<= 1) {
    int t = __shfl_up(s, off);
    if (lane >= off) s += t;
  }
  int excl = s - (v0 + v1);
  if (i0 < nb) bsum[i0] = excl;
  if (i1 < nb) bsum[i1] = excl + v0;
}

__global__ void k_scan_add(const int* __restrict__ incl, const int* __restrict__ bsum,
                           const int* __restrict__ deg,
                           int* __restrict__ offs, int* __restrict__ cursor, int n) {
  int i = blockIdx.x * blockDim.x + threadIdx.x;
  if (i < n) {
    int v = incl[i] + bsum[i >> 10];
    offs[i + 1] = v;
    cursor[i] = v - deg[i];
    if (i == 0) offs[0] = 0;
  }
}

__global__ void k_scatter(const int* __restrict__ src, const int* __restrict__ dst,
                          int* __restrict__ cursor, int* __restrict__ ssrc) {
  int e = blockIdx.x * blockDim.x + threadIdx.x;
  if (e < NE) {
    int pos = atomicAdd(&cursor[dst[e]], 1);
    ssrc[pos] = src[e];
  }
}

// ---------------- weight convert: fp32 [k][n] -> bf16 hi/lo planes [n][k] ----------------
__global__ void k_convw(const float* __restrict__ W_in, const float* __restrict__ W_gcr,
                        const float* __restrict__ W1, const float* __restrict__ W2,
                        ushort* __restrict__ Wt0h, ushort* __restrict__ Wt0l,
                        ushort* __restrict__ Wtgh, ushort* __restrict__ Wtgl,
                        ushort* __restrict__ Wt1h, ushort* __restrict__ Wt1l,
                        ushort* __restrict__ Wt2h, ushort* __restrict__ Wt2l) {
  int idx = blockIdx.x * blockDim.x + threadIdx.x;
  const int n0 = 256 * KPAD;
  const int n1 = n0 + 10 * 65536;
  const int n2 = n1 + DM1 * DH;
  const int n3 = n2 + DM2 * DM1;
  float v;
  ushort *dh, *dl;
  int o;
  if (idx < n0) {
    int n = idx / KPAD, k = idx - n * KPAD;
    v = (k < DIN) ? W_in[k * DH + n] : 0.f;
    dh = Wt0h; dl = Wt0l; o = idx;
  } else if (idx < n1) {
    int j = idx - n0;
    int l = j >> 16, r = j & 65535;
    int n = r >> 8, k = r & 255;
    v = W_gcr[l * 65536 + k * 256 + n];
    dh = Wtgh; dl = Wtgl; o = l * 65536 + n * 256 + k;
  } else if (idx < n2) {
    int j = idx - n1;
    int n = j >> 8, k = j & 255;
    v = W1[k * DM1 + n];
    dh = Wt1h; dl = Wt1l; o = n * 256 + k;
  } else if (idx < n3) {
    int j = idx - n2;
    int n = j >> 10, k = j & 1023;
    v = W2[k * DM2 + n];
    dh = Wt2h; dl = Wt2l; o = n * 1024 + k;
  } else {
    return;
  }
  ushort hv = f2bf(v);
  dh[o] = hv;
  dl[o] = f2bf(v - bf2f(hv));
}

// ---------------- SpMM (gather by dst row, wave per row) ----------------
__global__ void k_spmm74(const float* __restrict__ h, const int* __restrict__ offs,
                         const int* __restrict__ ssrc, const float* __restrict__ onorm,
                         const float* __restrict__ inorm,
                         ushort* __restrict__ Ahi, ushort* __restrict__ Alo) {
  int row = blockIdx.x * 4 + (threadIdx.x >> 6);
  if (row >= NN) return;
  int lane = threadIdx.x & 63;
  int beg = offs[row], end = offs[row + 1];
  float a0 = 0.f, a1 = 0.f;
  for (int e = beg; e < end; ++e) {
    int s = ssrc[e];
    float w = onorm[s];
    const float* hr = h + (size_t)s * DIN;
    a0 += w * hr[lane];
    if (lane < DIN - 64) a1 += w * hr[64 + lane];
  }
  float win = inorm[row];
  ushort* ph = Ahi + (size_t)row * KPAD;
  ushort* pl = Alo + (size_t)row * KPAD;
  float v0 = a0 * win;
  ushort h0 = f2bf(v0);
  ph[lane] = h0;
  pl[lane] = f2bf(v0 - bf2f(h0));
  if (lane < DIN - 64) {
    float v1 = a1 * win;
    ushort h1 = f2bf(v1);
    ph[64 + lane] = h1;
    pl[64 + lane] = f2bf(v1 - bf2f(h1));
  } else if (lane < KPAD - 64) {
    ph[64 + lane] = 0;
    pl[64 + lane] = 0;
  }
}

// gather bf16 hi-plane activations (2B/elem -> 512B/row), aggregate fp32,
// write m as hi/lo planes; depth-4 edge pipeline. 4 elems/lane (uint2).
__global__ void k_spmm256(const ushort* __restrict__ xh, const int* __restrict__ offs,
                          const int* __restrict__ ssrc, const float* __restrict__ onorm,
                          const float* __restrict__ inorm,
                          ushort* __restrict__ Ahi, ushort* __restrict__ Alo) {
  int row = blockIdx.x * 4 + (threadIdx.x >> 6);
  if (row >= NN) return;
  int lane = threadIdx.x & 63;
  int beg = offs[row], n = offs[row + 1] - beg;
  float a0 = 0.f, a1 = 0.f, a2 = 0.f, a3 = 0.f;
  float w0 = 0.f, w1 = 0.f, w2 = 0.f, w3 = 0.f;
  uint2 z = {0, 0};
  uint2 u0 = z, u1 = z, u2 = z, u3 = z;
#define LOADJ(wj, uj, idx) { int s_ = ssrc[idx]; wj = onorm[s_]; \
    uj = *(const uint2*)(xh + (size_t)s_ * DH + lane * 4); }
  if (n > 0) LOADJ(w0, u0, beg)
  if (n > 1) LOADJ(w1, u1, beg + 1)
  if (n > 2) LOADJ(w2, u2, beg + 2)
  if (n > 3) LOADJ(w3, u3, beg + 3)
  int e = 0;
#define STEP(wj, uj) { float fw = wj; uint2 fu = uj; \
    if (e + 4 < n) LOADJ(wj, uj, beg + e + 4) \
    a0 += fw * __uint_as_float(fu.x << 16); \
    a1 += fw * __uint_as_float(fu.x & 0xffff0000u); \
    a2 += fw * __uint_as_float(fu.y << 16); \
    a3 += fw * __uint_as_float(fu.y & 0xffff0000u); ++e; }
  while (e < n) {
    STEP(w0, u0) if (e >= n) break;
    STEP(w1, u1) if (e >= n) break;
    STEP(w2, u2) if (e >= n) break;
    STEP(w3, u3)
  }
#undef STEP
#undef LOADJ
  float win = inorm[row];
  float o[4] = {a0 * win, a1 * win, a2 * win, a3 * win};
  ushort4 hv, lv;
  hv.x = f2bf(o[0]); lv.x = f2bf(o[0] - bf2f(hv.x));
  hv.y = f2bf(o[1]); lv.y = f2bf(o[1] - bf2f(hv.y));
  hv.z = f2bf(o[2]); lv.z = f2bf(o[2] - bf2f(hv.z));
  hv.w = f2bf(o[3]); lv.w = f2bf(o[3] - bf2f(hv.w));
  *(ushort4*)(Ahi + (size_t)row * DH + lane * 4) = hv;
  *(ushort4*)(Alo + (size_t)row * DH + lane * 4) = lv;
}

// ---------------- async-staged bf16x3 MFMA GEMM, 128x256 tile, 512 threads ----------------
// A: hi/lo planes [M][K]; B: hi/lo planes [N][K] (k-contiguous). N tile 256 -> A read once.
// Staging via global_load_lds (16B/lane). XOR chunk swizzle -> free 2-way frag reads.
// ACT: 0=none 1=relu 2=leaky(0.01). OUT: 0=fp32 C0, 1=bf16 hi-plane C0, 2=planes C0/C1
template <int ACT, int OUT>
__global__ __launch_bounds__(512, 4) void k_mfma(
    const ushort* __restrict__ Ah, const ushort* __restrict__ Al,
    const ushort* __restrict__ Bh, const ushort* __restrict__ Bl,
    const float* __restrict__ bias, void* __restrict__ C0, void* __restrict__ C1,
    int M, int K, int Nc) {
  __shared__ __align__(16) ushort Ash[128 * 32], Asl[128 * 32];
  __shared__ __align__(16) ushort Bsh[256 * 32], Bsl[256 * 32];
  const int tid = threadIdx.x, lane = tid & 63, wv = tid >> 6;
  const int wm = (wv >> 2) * 64, wn = (wv & 3) * 64;
  const int quad = lane >> 4, l15 = lane & 15;
  const int r0 = blockIdx.x * 128, c0 = blockIdx.y * 256;

  // staging lane map: 16-row chunk per wave-issue; lane -> (row=lane>>2, chunk=lane&3)
  const int srow = lane >> 2, clds = lane & 3;
  const int arow = 16 * wv + srow;
  const int acg = clds ^ ((arow >> 1) & 3);            // global chunk landing at clds
  int agr = r0 + arow; if (agr > M - 1) agr = M - 1;   // clamp; epilogue masks stores
  const size_t aoff = (size_t)agr * K + acg * 8;
  const int brow0 = 16 * wv + srow, brow1 = brow0 + 128;
  const int bcg0 = clds ^ ((brow0 >> 1) & 3);
  const int bcg1 = clds ^ ((brow1 >> 1) & 3);
  const size_t boff0 = (size_t)(c0 + brow0) * K + bcg0 * 8;
  const size_t boff1 = (size_t)(c0 + brow1) * K + bcg1 * 8;
  ushort* lAh = &Ash[(16 * wv) * 32];
  ushort* lAl = &Asl[(16 * wv) * 32];
  ushort* lB0h = &Bsh[(16 * wv) * 32];
  ushort* lB0l = &Bsl[(16 * wv) * 32];
  ushort* lB1h = &Bsh[(16 * wv + 128) * 32];
  ushort* lB1l = &Bsl[(16 * wv + 128) * 32];

  f32x4 acc[4][4] = {};
  const int nk = K >> 5;
  for (int s = 0; s < nk; ++s) {
    const int k0 = s << 5;
    __syncthreads();  // previous tile fully consumed
    gll16(Ah + aoff + k0, lAh);
    gll16(Al + aoff + k0, lAl);
    gll16(Bh + boff0 + k0, lB0h);
    gll16(Bl + boff0 + k0, lB0l);
    gll16(Bh + boff1 + k0, lB1h);
    gll16(Bl + boff1 + k0, lB1l);
    __syncthreads();  // vmcnt drained by compiler before barrier -> tile visible
    short8 ah[4], al[4];
#pragma unroll
    for (int t = 0; t < 4; ++t) {
      int r = wm + t * 16 + l15;
      int sa = (quad ^ ((r >> 1) & 3)) << 3;
      ah[t] = *(const short8*)&Ash[r * 32 + sa];
      al[t] = *(const short8*)&Asl[r * 32 + sa];
    }
#pragma unroll
    for (int nt = 0; nt < 4; ++nt) {
      int rb = wn + nt * 16 + l15;
      int sb = (quad ^ ((rb >> 1) & 3)) << 3;
      short8 bh = *(const short8*)&Bsh[rb * 32 + sb];
      short8 bl = *(const short8*)&Bsl[rb * 32 + sb];
#pragma unroll
      for (int mt = 0; mt < 4; ++mt) {
        acc[mt][nt] = __builtin_amdgcn_mfma_f32_16x16x32_bf16(ah[mt], bh, acc[mt][nt], 0, 0, 0);
        acc[mt][nt] = __builtin_amdgcn_mfma_f32_16x16x32_bf16(ah[mt], bl, acc[mt][nt], 0, 0, 0);
        acc[mt][nt] = __builtin_amdgcn_mfma_f32_16x16x32_bf16(al[mt], bh, acc[mt][nt], 0, 0, 0);
      }
    }
  }

  float bv[4];
#pragma unroll
  for (int nt = 0; nt < 4; ++nt) bv[nt] = bias[c0 + wn + nt * 16 + l15];
#pragma unroll
  for (int mt = 0; mt < 4; ++mt) {
#pragma unroll
    for (int r = 0; r < 4; ++r) {
      int gr = r0 + wm + mt * 16 + quad * 4 + r;
      if (gr >= M) continue;
#pragma unroll
      for (int nt = 0; nt < 4; ++nt) {
        int gc = c0 + wn + nt * 16 + l15;
        float v = acc[mt][nt][r] + bv[nt];
        if (ACT == 1) v = fmaxf(v, 0.f);
        if (ACT == 2) v = (v > 0.f) ? v : 0.01f * v;
        size_t idx = (size_t)gr * Nc + gc;
        if (OUT == 0) {
          ((float*)C0)[idx] = v;
        } else if (OUT == 1) {
          ((ushort*)C0)[idx] = f2bf(v);
        } else {
          ushort hv = f2bf(v);
          ((ushort*)C0)[idx] = hv;
          ((ushort*)C1)[idx] = f2bf(v - bf2f(hv));
        }
      }
    }
  }
}

// ---------------- pooling + tail ----------------
__global__ void k_gbounds(const int* __restrict__ gid, int* __restrict__ gstart) {
  int g = blockIdx.x * blockDim.x + threadIdx.x;
  if (g > NG) return;
  int lo = 0, hi = NN;
  while (lo < hi) {
    int mid = (lo + hi) >> 1;
    if (gid[mid] < g) lo = mid + 1; else hi = mid;
  }
  gstart[g] = lo;
}

__global__ void k_pool(const ushort* __restrict__ xh, const int* __restrict__ gstart,
                       ushort* __restrict__ ph, ushort* __restrict__ pl) {
  int g = blockIdx.x * 4 + (threadIdx.x >> 6);
  if (g >= NG) return;
  int lane = threadIdx.x & 63;
  int beg = gstart[g], end = gstart[g + 1];
  float a0 = 0.f, a1 = 0.f, a2 = 0.f, a3 = 0.f;
  for (int r = beg; r < end; ++r) {
    uint2 u = *(const uint2*)(xh + (size_t)r * DH + lane * 4);
    a0 += __uint_as_float(u.x << 16);
    a1 += __uint_as_float(u.x & 0xffff0000u);
    a2 += __uint_as_float(u.y << 16);
    a3 += __uint_as_float(u.y & 0xffff0000u);
  }
  float inv = 1.f / fmaxf((float)(end - beg), 1.f);
  float o[4] = {a0 * inv, a1 * inv, a2 * inv, a3 * inv};
  ushort4 hv, lv;
  hv.x = f2bf(o[0]); lv.x = f2bf(o[0] - bf2f(hv.x));
  hv.y = f2bf(o[1]); lv.y = f2bf(o[1] - bf2f(hv.y));
  hv.z = f2bf(o[2]); lv.z = f2bf(o[2] - bf2f(hv.z));
  hv.w = f2bf(o[3]); lv.w = f2bf(o[3] - bf2f(hv.w));
  *(ushort4*)(ph + (size_t)g * DH + lane * 4) = hv;
  *(ushort4*)(pl + (size_t)g * DH + lane * 4) = lv;
}

__global__ void k_out(const float* __restrict__ z2, const float* __restrict__ W3,
                      const float* __restrict__ b3, float* __restrict__ out) {
  int g = blockIdx.x * 4 + (threadIdx.x >> 6);
  if (g >= NG) return;
  int lane = threadIdx.x & 63;
  float s = 0.f;
  const float* zr = z2 + (size_t)g * DM2;
  for (int k = lane; k < DM2; k += 64) s += zr[k] * W3[k];
  for (int off = 32; off > 0; off >>= 1) s += __shfl_down(s, off);
  if (lane == 0) out[g] = s + b3[0];
}

// ---------------- launcher ----------------
extern "C" void kernel_launch(void* const* d_in, const int* in_sizes, int n_in,
                              void* d_out, int out_size, void* d_ws, size_t ws_size,
                              hipStream_t stream) {
  (void)in_sizes; (void)n_in; (void)out_size; (void)ws_size;
  const float* h     = (const float*)d_in[0];
  const int*   src   = (const int*)d_in[1];
  const int*   dst   = (const int*)d_in[2];
  const int*   gid   = (const int*)d_in[3];
  const float* W_in  = (const float*)d_in[4];
  const float* b_in  = (const float*)d_in[5];
  const float* W_gcr = (const float*)d_in[6];
  const float* b_gcr = (const float*)d_in[7];
  const float* W1    = (const float*)d_in[8];
  const float* b1    = (const float*)d_in[9];
  const float* W2    = (const float*)d_in[10];
  const float* b2    = (const float*)d_in[11];
  const float* W3    = (const float*)d_in[12];
  const float* b3    = (const float*)d_in[13];
  float* out = (float*)d_out;

  char* p = (char*)d_ws;
  auto alloc = [&](size_t bytes) {
    char* q = p;
    p += (bytes + 255) & ~(size_t)255;
    return q;
  };
  int*    outdeg = (int*)alloc((size_t)NN * 4);
  int*    indeg  = (int*)alloc((size_t)NN * 4);
  float*  onorm  = (float*)alloc((size_t)NN * 4);
  float*  inorm  = (float*)alloc((size_t)NN * 4);
  int*    incl   = (int*)alloc((size_t)NN * 4);
  int*    bsum   = (int*)alloc(128 * 4);
  int*    offs   = (int*)alloc((size_t)(NN + 1) * 4);
  int*    cursor = (int*)alloc((size_t)NN * 4);
  int*    ssrc   = (int*)alloc((size_t)NE * 4);
  int*    gstart = (int*)alloc((size_t)(NG + 1) * 4);
  ushort* xh     = (ushort*)alloc((size_t)NN * DH * 2);
  ushort* Ahi    = (ushort*)alloc((size_t)NN * DH * 2);
  ushort* Alo    = (ushort*)alloc((size_t)NN * DH * 2);
  ushort* Wt0h   = (ushort*)alloc((size_t)256 * KPAD * 2);
  ushort* Wt0l   = (ushort*)alloc((size_t)256 * KPAD * 2);
  ushort* Wtgh   = (ushort*)alloc((size_t)10 * 65536 * 2);
  ushort* Wtgl   = (ushort*)alloc((size_t)10 * 65536 * 2);
  ushort* Wt1h   = (ushort*)alloc((size_t)DM1 * DH * 2);
  ushort* Wt1l   = (ushort*)alloc((size_t)DM1 * DH * 2);
  ushort* Wt2h   = (ushort*)alloc((size_t)DM2 * DM1 * 2);
  ushort* Wt2l   = (ushort*)alloc((size_t)DM2 * DM1 * 2);
  ushort* plh    = (ushort*)alloc((size_t)NG * DH * 2);
  ushort* pll    = (ushort*)alloc((size_t)NG * DH * 2);
  ushort* z1h    = (ushort*)alloc((size_t)NG * DM1 * 2);
  ushort* z1l    = (ushort*)alloc((size_t)NG * DM1 * 2);
  float*  z2     = (float*)alloc((size_t)NG * DM2 * 4);

  hipMemsetAsync(outdeg, 0, (size_t)NN * 4, stream);
  hipMemsetAsync(indeg, 0, (size_t)NN * 4, stream);
  k_deg<<<(NE + 255) / 256, 256, 0, stream>>>(src, dst, outdeg, indeg);
  k_norm<<<(NN + 255) / 256, 256, 0, stream>>>(outdeg, indeg, onorm, inorm);
  int nb = (NN + 1023) / 1024;
  k_scan_block<<<nb, 1024, 0, stream>>>(indeg, incl, bsum, NN);
  k_scan_sums<<<1, 64, 0, stream>>>(bsum, nb);
  k_scan_add<<<(NN + 255) / 256, 256, 0, stream>>>(incl, bsum, indeg, offs, cursor, NN);
  k_scatter<<<(NE + 255) / 256, 256, 0, stream>>>(src, dst, cursor, ssrc);

  const int nconv = 256 * KPAD + 10 * 65536 + DM1 * DH + DM2 * DM1;
  k_convw<<<(nconv + 255) / 256, 256, 0, stream>>>(W_in, W_gcr, W1, W2,
                                                   Wt0h, Wt0l, Wtgh, Wtgl,
                                                   Wt1h, Wt1l, Wt2h, Wt2l);

  dim3 gmm((NN + 127) / 128, 1);  // N=256 covered by one column tile

  // input conv: aggregate 74 (pad 96), GEMM 96->256, no activation, bf16-hi output
  k_spmm74<<<(NN + 3) / 4, 256, 0, stream>>>(h, offs, ssrc, onorm, inorm, Ahi, Alo);
  k_mfma<0, 1><<<gmm, 512, 0, stream>>>(Ahi, Alo, Wt0h, Wt0l, b_in, xh, nullptr,
                                        NN, KPAD, DH);

  // 5 GCR blocks x 2 convs; relu fused into every conv GEMM epilogue
  for (int li = 0; li < 10; ++li) {
    k_spmm256<<<(NN + 3) / 4, 256, 0, stream>>>(xh, offs, ssrc, onorm, inorm, Ahi, Alo);
    k_mfma<1, 1><<<gmm, 512, 0, stream>>>(Ahi, Alo, Wtgh + (size_t)li * 65536,
                                          Wtgl + (size_t)li * 65536, b_gcr + li * 256,
                                          xh, nullptr, NN, DH, DH);
  }

  k_gbounds<<<(NG + 1 + 255) / 256, 256, 0, stream>>>(gid, gstart);
  k_pool<<<(NG + 3) / 4, 256, 0, stream>>>(xh, gstart, plh, pll);

  dim3 gt1(NG / 128, DM1 / 256);
  k_mfma<2, 2><<<gt1, 512, 0, stream>>>(plh, pll, Wt1h, Wt1l, b1, z1h, z1l,
                                        NG, DH, DM1);
  dim3 gt2(NG / 128, DM2 / 256);
  k_mfma<2, 0><<<gt2, 512, 0, stream>>>(z1h, z1l, Wt2h, Wt2l, b2, z2, nullptr,
                                        NG, DM1, DM2);
  k_out<<<(NG + 3) / 4, 256, 0, stream>>>(z2, W3, b3, out);
}